// Round 3
// baseline (56.798 us; speedup 1.0000x reference)
//
#include <hip/hip_runtime.h>
#include <math.h>

// MoE gate: logits = x @ W^T (T=131072, D=512, E=4), fp32 softmax,
// top-2 of (softmax + bias), gathered softmax weights + indices.
// Memory-bound (256 MiB x-read). One wave per token-pair, dense per-
// instruction float4 loads (ext_vector_type for nontemporal builtin),
// weights in registers, interleaved butterfly reductions, float4 stores.

constexpr int TOKENS = 131072;
constexpr int DIM = 512;
constexpr int CHUNK = 16;   // tokens per wave (contiguous)

typedef float fvec4 __attribute__((ext_vector_type(4)));

__global__ __launch_bounds__(256, 4) void gate_kernel(
    const float* __restrict__ x,      // [T, D]
    const float* __restrict__ w,      // [E, D]
    const float* __restrict__ bias,   // [E]
    float* __restrict__ out_w,        // [T, 2] fp32
    float* __restrict__ out_i)        // [T, 2] indices as float
{
    const int lane = threadIdx.x & 63;
    const int wave = blockIdx.x * (blockDim.x >> 6) + (threadIdx.x >> 6);
    const int t0   = wave * CHUNK;

    // Lane's column slices: [4*lane .. 4*lane+3] and [256+4*lane .. +3].
    // Each load instruction covers a dense contiguous 1 KiB across the wave.
    const int cLo = 4 * lane;
    const int cHi = 256 + 4 * lane;

    const fvec4 w0a = *reinterpret_cast<const fvec4*>(w + 0 * DIM + cLo);
    const fvec4 w0b = *reinterpret_cast<const fvec4*>(w + 0 * DIM + cHi);
    const fvec4 w1a = *reinterpret_cast<const fvec4*>(w + 1 * DIM + cLo);
    const fvec4 w1b = *reinterpret_cast<const fvec4*>(w + 1 * DIM + cHi);
    const fvec4 w2a = *reinterpret_cast<const fvec4*>(w + 2 * DIM + cLo);
    const fvec4 w2b = *reinterpret_cast<const fvec4*>(w + 2 * DIM + cHi);
    const fvec4 w3a = *reinterpret_cast<const fvec4*>(w + 3 * DIM + cLo);
    const fvec4 w3b = *reinterpret_cast<const fvec4*>(w + 3 * DIM + cHi);
    const float b0 = bias[0], b1 = bias[1], b2 = bias[2], b3 = bias[3];

    #pragma unroll
    for (int j = 0; j < CHUNK; j += 2) {
        const int tA = t0 + j;
        const int tB = tA + 1;
        const float* rowA = x + (size_t)tA * DIM;
        const float* rowB = x + (size_t)tB * DIM;

        // 4 independent dwordx4 loads issued back-to-back (2 tokens in flight)
        const fvec4 xa0 = __builtin_nontemporal_load(reinterpret_cast<const fvec4*>(rowA + cLo));
        const fvec4 xa1 = __builtin_nontemporal_load(reinterpret_cast<const fvec4*>(rowA + cHi));
        const fvec4 xb0 = __builtin_nontemporal_load(reinterpret_cast<const fvec4*>(rowB + cLo));
        const fvec4 xb1 = __builtin_nontemporal_load(reinterpret_cast<const fvec4*>(rowB + cHi));

        float A0 = xa0.x*w0a.x + xa0.y*w0a.y + xa0.z*w0a.z + xa0.w*w0a.w
                 + xa1.x*w0b.x + xa1.y*w0b.y + xa1.z*w0b.z + xa1.w*w0b.w;
        float A1 = xa0.x*w1a.x + xa0.y*w1a.y + xa0.z*w1a.z + xa0.w*w1a.w
                 + xa1.x*w1b.x + xa1.y*w1b.y + xa1.z*w1b.z + xa1.w*w1b.w;
        float A2 = xa0.x*w2a.x + xa0.y*w2a.y + xa0.z*w2a.z + xa0.w*w2a.w
                 + xa1.x*w2b.x + xa1.y*w2b.y + xa1.z*w2b.z + xa1.w*w2b.w;
        float A3 = xa0.x*w3a.x + xa0.y*w3a.y + xa0.z*w3a.z + xa0.w*w3a.w
                 + xa1.x*w3b.x + xa1.y*w3b.y + xa1.z*w3b.z + xa1.w*w3b.w;

        float B0 = xb0.x*w0a.x + xb0.y*w0a.y + xb0.z*w0a.z + xb0.w*w0a.w
                 + xb1.x*w0b.x + xb1.y*w0b.y + xb1.z*w0b.z + xb1.w*w0b.w;
        float B1 = xb0.x*w1a.x + xb0.y*w1a.y + xb0.z*w1a.z + xb0.w*w1a.w
                 + xb1.x*w1b.x + xb1.y*w1b.y + xb1.z*w1b.z + xb1.w*w1b.w;
        float B2 = xb0.x*w2a.x + xb0.y*w2a.y + xb0.z*w2a.z + xb0.w*w2a.w
                 + xb1.x*w2b.x + xb1.y*w2b.y + xb1.z*w2b.z + xb1.w*w2b.w;
        float B3 = xb0.x*w3a.x + xb0.y*w3a.y + xb0.z*w3a.z + xb0.w*w3a.w
                 + xb1.x*w3b.x + xb1.y*w3b.y + xb1.z*w3b.z + xb1.w*w3b.w;

        // Interleaved butterfly reductions: two independent 6-deep chains.
        #pragma unroll
        for (int off = 1; off < 64; off <<= 1) {
            A0 += __shfl_xor(A0, off, 64);
            B0 += __shfl_xor(B0, off, 64);
            A1 += __shfl_xor(A1, off, 64);
            B1 += __shfl_xor(B1, off, 64);
            A2 += __shfl_xor(A2, off, 64);
            B2 += __shfl_xor(B2, off, 64);
            A3 += __shfl_xor(A3, off, 64);
            B3 += __shfl_xor(B3, off, 64);
        }

        // --- softmax epilogues (all lanes redundantly; lane 0 stores) ---
        float sA0, sA1, sA2, sA3;
        {
            const float m  = fmaxf(fmaxf(A0, A1), fmaxf(A2, A3));
            const float e0 = __expf(A0 - m), e1 = __expf(A1 - m);
            const float e2 = __expf(A2 - m), e3 = __expf(A3 - m);
            const float inv = 1.0f / (e0 + e1 + e2 + e3);
            sA0 = e0 * inv; sA1 = e1 * inv; sA2 = e2 * inv; sA3 = e3 * inv;
        }
        float sB0, sB1, sB2, sB3;
        {
            const float m  = fmaxf(fmaxf(B0, B1), fmaxf(B2, B3));
            const float e0 = __expf(B0 - m), e1 = __expf(B1 - m);
            const float e2 = __expf(B2 - m), e3 = __expf(B3 - m);
            const float inv = 1.0f / (e0 + e1 + e2 + e3);
            sB0 = e0 * inv; sB1 = e1 * inv; sB2 = e2 * inv; sB3 = e3 * inv;
        }

        // top-2 selection on biased scores (strict > keeps lowest index on ties)
        const float pA0 = sA0 + b0, pA1 = sA1 + b1, pA2 = sA2 + b2, pA3 = sA3 + b3;
        int   iA0 = 0; float bvA = pA0, svA0 = sA0;
        if (pA1 > bvA) { bvA = pA1; svA0 = sA1; iA0 = 1; }
        if (pA2 > bvA) { bvA = pA2; svA0 = sA2; iA0 = 2; }
        if (pA3 > bvA) { bvA = pA3; svA0 = sA3; iA0 = 3; }
        int   iA1 = -1; float bvA1 = -INFINITY, svA1 = 0.0f;
        if (iA0 != 0 && pA0 > bvA1) { bvA1 = pA0; svA1 = sA0; iA1 = 0; }
        if (iA0 != 1 && pA1 > bvA1) { bvA1 = pA1; svA1 = sA1; iA1 = 1; }
        if (iA0 != 2 && pA2 > bvA1) { bvA1 = pA2; svA1 = sA2; iA1 = 2; }
        if (iA0 != 3 && pA3 > bvA1) { bvA1 = pA3; svA1 = sA3; iA1 = 3; }

        const float pB0 = sB0 + b0, pB1 = sB1 + b1, pB2 = sB2 + b2, pB3 = sB3 + b3;
        int   iB0 = 0; float bvB = pB0, svB0 = sB0;
        if (pB1 > bvB) { bvB = pB1; svB0 = sB1; iB0 = 1; }
        if (pB2 > bvB) { bvB = pB2; svB0 = sB2; iB0 = 2; }
        if (pB3 > bvB) { bvB = pB3; svB0 = sB3; iB0 = 3; }
        int   iB1 = -1; float bvB1 = -INFINITY, svB1 = 0.0f;
        if (iB0 != 0 && pB0 > bvB1) { bvB1 = pB0; svB1 = sB0; iB1 = 0; }
        if (iB0 != 1 && pB1 > bvB1) { bvB1 = pB1; svB1 = sB1; iB1 = 1; }
        if (iB0 != 2 && pB2 > bvB1) { bvB1 = pB2; svB1 = sB2; iB1 = 2; }
        if (iB0 != 3 && pB3 > bvB1) { bvB1 = pB3; svB1 = sB3; iB1 = 3; }

        if (lane == 0) {
            fvec4 wv; wv.x = svA0; wv.y = svA1; wv.z = svB0; wv.w = svB1;
            fvec4 iv; iv.x = (float)iA0; iv.y = (float)iA1; iv.z = (float)iB0; iv.w = (float)iB1;
            *reinterpret_cast<fvec4*>(out_w + 2 * (size_t)tA) = wv;
            *reinterpret_cast<fvec4*>(out_i + 2 * (size_t)tA) = iv;
        }
    }
}

extern "C" void kernel_launch(void* const* d_in, const int* in_sizes, int n_in,
                              void* d_out, int out_size, void* d_ws, size_t ws_size,
                              hipStream_t stream) {
    const float* x    = (const float*)d_in[0];
    const float* w    = (const float*)d_in[1];
    const float* bias = (const float*)d_in[2];

    float* out_w = (float*)d_out;                      // [T,2] weights
    float* out_i = (float*)d_out + (size_t)TOKENS * 2; // [T,2] indices (as float)

    const int block  = 256;                  // 4 waves/block
    const int blocks = TOKENS / (CHUNK * 4); // 2048 blocks -> 8192 waves
    gate_kernel<<<blocks, block, 0, stream>>>(x, w, bias, out_w, out_i);
}

// Round 4
// 50.127 us; speedup vs baseline: 1.1331x; 1.1331x over previous
//
#include <hip/hip_runtime.h>
#include <math.h>

// MoE gate: logits = x @ W^T (T=131072, D=512, E=4), fp32 softmax,
// top-2 of (softmax + bias), gathered softmax weights + indices.
// Memory-bound (256 MiB x-read). R1 structure (grid-stride interleave,
// plain float4 loads) + ONE change: token-pair per iteration for 2x MLP
// and merged float4 stores.

constexpr int TOKENS = 131072;
constexpr int DIM = 512;

typedef float fvec4 __attribute__((ext_vector_type(4)));

__global__ __launch_bounds__(256) void gate_kernel(
    const float* __restrict__ x,      // [T, D]
    const float* __restrict__ w,      // [E, D]
    const float* __restrict__ bias,   // [E]
    float* __restrict__ out_w,        // [T, 2] fp32
    float* __restrict__ out_i)        // [T, 2] indices as float
{
    const int lane   = threadIdx.x & 63;
    const int wavesPerBlock = blockDim.x >> 6;
    const int wave   = blockIdx.x * wavesPerBlock + (threadIdx.x >> 6);
    const int nwaves = gridDim.x * wavesPerBlock;

    // Lane's slice: w[e][lane*8 .. lane*8+7] (two consecutive float4s)
    const float4 w0a = *reinterpret_cast<const float4*>(w + 0 * DIM + lane * 8);
    const float4 w0b = *reinterpret_cast<const float4*>(w + 0 * DIM + lane * 8 + 4);
    const float4 w1a = *reinterpret_cast<const float4*>(w + 1 * DIM + lane * 8);
    const float4 w1b = *reinterpret_cast<const float4*>(w + 1 * DIM + lane * 8 + 4);
    const float4 w2a = *reinterpret_cast<const float4*>(w + 2 * DIM + lane * 8);
    const float4 w2b = *reinterpret_cast<const float4*>(w + 2 * DIM + lane * 8 + 4);
    const float4 w3a = *reinterpret_cast<const float4*>(w + 3 * DIM + lane * 8);
    const float4 w3b = *reinterpret_cast<const float4*>(w + 3 * DIM + lane * 8 + 4);
    const float b0 = bias[0], b1 = bias[1], b2 = bias[2], b3 = bias[3];

    // Grid-stride over token PAIRS: consecutive waves handle adjacent pairs,
    // so the whole chip sweeps one dense window at every instant.
    for (int tp = wave; tp < TOKENS / 2; tp += nwaves) {
        const int tA = tp * 2;
        const int tB = tA + 1;
        const float4* pA = reinterpret_cast<const float4*>(x + (size_t)tA * DIM + lane * 8);
        const float4* pB = reinterpret_cast<const float4*>(x + (size_t)tB * DIM + lane * 8);

        // 4 independent dwordx4 loads in flight
        const float4 xa0 = pA[0];
        const float4 xa1 = pA[1];
        const float4 xb0 = pB[0];
        const float4 xb1 = pB[1];

        float A0 = xa0.x*w0a.x + xa0.y*w0a.y + xa0.z*w0a.z + xa0.w*w0a.w
                 + xa1.x*w0b.x + xa1.y*w0b.y + xa1.z*w0b.z + xa1.w*w0b.w;
        float A1 = xa0.x*w1a.x + xa0.y*w1a.y + xa0.z*w1a.z + xa0.w*w1a.w
                 + xa1.x*w1b.x + xa1.y*w1b.y + xa1.z*w1b.z + xa1.w*w1b.w;
        float A2 = xa0.x*w2a.x + xa0.y*w2a.y + xa0.z*w2a.z + xa0.w*w2a.w
                 + xa1.x*w2b.x + xa1.y*w2b.y + xa1.z*w2b.z + xa1.w*w2b.w;
        float A3 = xa0.x*w3a.x + xa0.y*w3a.y + xa0.z*w3a.z + xa0.w*w3a.w
                 + xa1.x*w3b.x + xa1.y*w3b.y + xa1.z*w3b.z + xa1.w*w3b.w;

        float B0 = xb0.x*w0a.x + xb0.y*w0a.y + xb0.z*w0a.z + xb0.w*w0a.w
                 + xb1.x*w0b.x + xb1.y*w0b.y + xb1.z*w0b.z + xb1.w*w0b.w;
        float B1 = xb0.x*w1a.x + xb0.y*w1a.y + xb0.z*w1a.z + xb0.w*w1a.w
                 + xb1.x*w1b.x + xb1.y*w1b.y + xb1.z*w1b.z + xb1.w*w1b.w;
        float B2 = xb0.x*w2a.x + xb0.y*w2a.y + xb0.z*w2a.z + xb0.w*w2a.w
                 + xb1.x*w2b.x + xb1.y*w2b.y + xb1.z*w2b.z + xb1.w*w2b.w;
        float B3 = xb0.x*w3a.x + xb0.y*w3a.y + xb0.z*w3a.z + xb0.w*w3a.w
                 + xb1.x*w3b.x + xb1.y*w3b.y + xb1.z*w3b.z + xb1.w*w3b.w;

        // Interleaved butterfly reductions: two independent 6-deep chains.
        #pragma unroll
        for (int off = 1; off < 64; off <<= 1) {
            A0 += __shfl_xor(A0, off, 64);
            B0 += __shfl_xor(B0, off, 64);
            A1 += __shfl_xor(A1, off, 64);
            B1 += __shfl_xor(B1, off, 64);
            A2 += __shfl_xor(A2, off, 64);
            B2 += __shfl_xor(B2, off, 64);
            A3 += __shfl_xor(A3, off, 64);
            B3 += __shfl_xor(B3, off, 64);
        }

        // --- softmax epilogues (all lanes redundantly; lane 0 stores) ---
        float sA0, sA1, sA2, sA3;
        {
            const float m  = fmaxf(fmaxf(A0, A1), fmaxf(A2, A3));
            const float e0 = __expf(A0 - m), e1 = __expf(A1 - m);
            const float e2 = __expf(A2 - m), e3 = __expf(A3 - m);
            const float inv = 1.0f / (e0 + e1 + e2 + e3);
            sA0 = e0 * inv; sA1 = e1 * inv; sA2 = e2 * inv; sA3 = e3 * inv;
        }
        float sB0, sB1, sB2, sB3;
        {
            const float m  = fmaxf(fmaxf(B0, B1), fmaxf(B2, B3));
            const float e0 = __expf(B0 - m), e1 = __expf(B1 - m);
            const float e2 = __expf(B2 - m), e3 = __expf(B3 - m);
            const float inv = 1.0f / (e0 + e1 + e2 + e3);
            sB0 = e0 * inv; sB1 = e1 * inv; sB2 = e2 * inv; sB3 = e3 * inv;
        }

        // top-2 on biased scores (strict > keeps lowest index on ties)
        const float pA0s = sA0 + b0, pA1s = sA1 + b1, pA2s = sA2 + b2, pA3s = sA3 + b3;
        int   iA0 = 0; float bvA = pA0s, svA0 = sA0;
        if (pA1s > bvA) { bvA = pA1s; svA0 = sA1; iA0 = 1; }
        if (pA2s > bvA) { bvA = pA2s; svA0 = sA2; iA0 = 2; }
        if (pA3s > bvA) { bvA = pA3s; svA0 = sA3; iA0 = 3; }
        int   iA1 = -1; float bvA1 = -INFINITY, svA1 = 0.0f;
        if (iA0 != 0 && pA0s > bvA1) { bvA1 = pA0s; svA1 = sA0; iA1 = 0; }
        if (iA0 != 1 && pA1s > bvA1) { bvA1 = pA1s; svA1 = sA1; iA1 = 1; }
        if (iA0 != 2 && pA2s > bvA1) { bvA1 = pA2s; svA1 = sA2; iA1 = 2; }
        if (iA0 != 3 && pA3s > bvA1) { bvA1 = pA3s; svA1 = sA3; iA1 = 3; }

        const float pB0s = sB0 + b0, pB1s = sB1 + b1, pB2s = sB2 + b2, pB3s = sB3 + b3;
        int   iB0 = 0; float bvB = pB0s, svB0 = sB0;
        if (pB1s > bvB) { bvB = pB1s; svB0 = sB1; iB0 = 1; }
        if (pB2s > bvB) { bvB = pB2s; svB0 = sB2; iB0 = 2; }
        if (pB3s > bvB) { bvB = pB3s; svB0 = sB3; iB0 = 3; }
        int   iB1 = -1; float bvB1 = -INFINITY, svB1 = 0.0f;
        if (iB0 != 0 && pB0s > bvB1) { bvB1 = pB0s; svB1 = sB0; iB1 = 0; }
        if (iB0 != 1 && pB1s > bvB1) { bvB1 = pB1s; svB1 = sB1; iB1 = 1; }
        if (iB0 != 2 && pB2s > bvB1) { bvB1 = pB2s; svB1 = sB2; iB1 = 2; }
        if (iB0 != 3 && pB3s > bvB1) { bvB1 = pB3s; svB1 = sB3; iB1 = 3; }

        if (lane == 0) {
            fvec4 wv; wv.x = svA0; wv.y = svA1; wv.z = svB0; wv.w = svB1;
            fvec4 iv; iv.x = (float)iA0; iv.y = (float)iA1; iv.z = (float)iB0; iv.w = (float)iB1;
            *reinterpret_cast<fvec4*>(out_w + 2 * (size_t)tA) = wv;
            *reinterpret_cast<fvec4*>(out_i + 2 * (size_t)tA) = iv;
        }
    }
}

extern "C" void kernel_launch(void* const* d_in, const int* in_sizes, int n_in,
                              void* d_out, int out_size, void* d_ws, size_t ws_size,
                              hipStream_t stream) {
    const float* x    = (const float*)d_in[0];
    const float* w    = (const float*)d_in[1];
    const float* bias = (const float*)d_in[2];

    float* out_w = (float*)d_out;                      // [T,2] weights
    float* out_i = (float*)d_out + (size_t)TOKENS * 2; // [T,2] indices (as float)

    const int block  = 256;   // 4 waves/block
    const int blocks = 2048;  // 8192 waves -> 8 pair-iterations/wave
    gate_kernel<<<blocks, block, 0, stream>>>(x, w, bias, out_w, out_i);
}